// Round 4
// baseline (1136.243 us; speedup 1.0000x reference)
//
#include <hip/hip_runtime.h>

// ---------------- problem constants ----------------
#define N_WORDS 16384
#define MAXL    16
#define VOCABSZ 128
#define EMBD    64
#define HID     256
#define GATES   1024        // 4*HID
#define KTOT    320         // HID + EMBD (x folded into K)
#define AROW    328         // A row stride in shorts (656 B = 640 + 16 pad)
#define M_TILE  64          // words per workgroup
#define NT      256         // word tiles (N_WORDS / M_TILE)

typedef __attribute__((ext_vector_type(8))) short bf16x8;  // 8 bf16 = 4 VGPRs
typedef __attribute__((ext_vector_type(4))) float f32x4;
typedef __attribute__((ext_vector_type(4))) int   i32x4;

// ---------------- workspace layout (bytes) ----------------
// wsw : swizzled weights, A-fragment order: [dir][R 0..63][kk 0..9][lane 0..63][8 bf16]
#define OFF_WSW   0ul          // 2*64*10*64*16 = 1310720
#define OFF_EMB   1310720ul    // 128*64 bf16 = 16384
#define OFF_BIAS  1327104ul    // 2*1024 f32 = 8192 (interleaved unit-major: [4*unit+type])
#define OFF_SORT  1335296ul    // 16384 ints = 65536
#define OFF_HIST  1400832ul    // 16 ints
#define OFF_BASE  1400896ul    // 16 ints
#define OFF_CNT   1400960ul    // 16 ints
// cell state lives in LDS (64 KB/block) -- no global c buffer

__device__ inline short tobf(float f) {           // fp32 -> bf16 RNE
  unsigned u = __float_as_uint(f);
  unsigned r = (u + 0x7fffu + ((u >> 16) & 1u)) >> 16;
  return (short)r;
}
// raw transcendental units via inline asm
__device__ inline float aexp2(float x) { float r; asm("v_exp_f32 %0, %1" : "=v"(r) : "v"(x)); return r; }
__device__ inline float arcp(float x)  { float r; asm("v_rcp_f32 %0, %1" : "=v"(r) : "v"(x)); return r; }
__device__ inline float fsig(float x)   { return arcp(1.0f + aexp2(x * -1.4426950408889634f)); }
__device__ inline float ftanhf(float x) { return 1.0f - 2.0f * arcp(1.0f + aexp2(x * 2.8853900817779268f)); }

// ---------------- prep: weight swizzle into MFMA *A*-fragment layout ----------------
// A[m][k] for 16x16x32: m = lane&15, k = kk*32 + (lane>>4)*8 + j
// row m of row-tile R: unit = 4R + (m>>2), gate type = m&3, gate row g = type*256 + unit
__global__ void prep_w(const float* __restrict__ Wihf, const float* __restrict__ Whhf,
                       const float* __restrict__ Wihb, const float* __restrict__ Whhb,
                       short* __restrict__ wsw) {
  int id = blockIdx.x * 256 + threadIdx.x;       // 2*64*10*64 = 81920
  if (id >= 81920) return;
  int d    = id / 40960;
  int r    = id % 40960;
  int R    = r / 640;
  int r2   = r % 640;
  int kk   = r2 / 64;
  int lane = r2 % 64;
  int m    = lane & 15;
  int unit = R * 4 + (m >> 2);
  int ty   = m & 3;
  int g    = ty * 256 + unit;
  int kb   = kk * 32 + (lane >> 4) * 8;
  const float* Wih = d ? Wihb : Wihf;
  const float* Whh = d ? Whhb : Whhf;
  bf16x8 v;
#pragma unroll
  for (int j = 0; j < 8; ++j) {
    int k = kb + j;
    float f = (k < HID) ? Whh[g * HID + k] : Wih[g * EMBD + (k - HID)];
    v[j] = tobf(f);
  }
  ((bf16x8*)wsw)[id] = v;
}

// emb -> bf16, biases -> interleaved sum ([4*unit+type], matches C-row interleave)
__global__ void prep_misc(const float* __restrict__ emb,
                          const float* __restrict__ bihf, const float* __restrict__ bhhf,
                          const float* __restrict__ bihb, const float* __restrict__ bhhb,
                          short* __restrict__ embw, float* __restrict__ biasg) {
  int id = blockIdx.x * 256 + threadIdx.x;       // 8192 + 2048 = 10240
  if (id < VOCABSZ * EMBD) {
    embw[id] = tobf(emb[id]);
  } else {
    int r = id - VOCABSZ * EMBD;
    if (r < 2048) {
      int d = r >> 10, n = r & 1023;
      int g = (n & 3) * 256 + (n >> 2);
      biasg[r] = d ? (bihb[g] + bhhb[g]) : (bihf[g] + bhhf[g]);
    }
  }
}

// ---------------- length bucketing ----------------
__global__ void k_hist(const int* __restrict__ lengths, int* __restrict__ hist) {
  int id = blockIdx.x * 256 + threadIdx.x;
  if (id < N_WORDS) atomicAdd(&hist[lengths[id] - 1], 1);
}
__global__ void k_scan(const int* __restrict__ hist, int* __restrict__ basep) {
  if (threadIdx.x == 0 && blockIdx.x == 0) {
    int s = 0;
    for (int i = 0; i < 16; ++i) { basep[i] = s; s += hist[i]; }
  }
}
__global__ void k_scat(const int* __restrict__ lengths, const int* __restrict__ basep,
                       int* __restrict__ cnt, int* __restrict__ sorted) {
  int id = blockIdx.x * 256 + threadIdx.x;
  if (id < N_WORDS) {
    int b = lengths[id] - 1;
    int p = basep[b] + atomicAdd(&cnt[b], 1);
    sorted[p] = id;
  }
}

// ---------------- main fused BiLSTM kernel (v3 resubmit: infra flake in R3) ----
// Weights = MFMA A-operand (rows = 4 units x 4 gates, unit-major), [h|x] = B-operand.
// lane owns: unit u = 32*wv + 4*rt + quad, word w = ct*16 + colc; acc regs = i,f,g,o.
// Cell state: LDS f32x4 per (wv,rt,lane). hx B-fragments register-resident per step.
// Pipeline per step (T15 analog): mfma(rt) -> ldw(rt+1) -> epi(rt-1); epilogue VALU
// runs under next tile's MFMA + covers the single-buffered weight-load latency.
__global__ __launch_bounds__(512, 1) void lstm_main(
    const int* __restrict__ char_ids, const int* __restrict__ lengths,
    const short* __restrict__ wsw, const short* __restrict__ embw,
    const float* __restrict__ biasg, const int* __restrict__ sorted,
    float* __restrict__ out) {
  __shared__ __align__(16) short A[M_TILE * AROW];   // [word][ h(256) | x(64) | pad(8) ] bf16
  __shared__ __align__(16) int   charl[M_TILE * 16];
  __shared__ __align__(16) float biasl[GATES];
  __shared__ __align__(16) f32x4 c4[8 * 8 * 64];     // [wv][rt][lane] cell state, 64 KB
  __shared__ int lenl[M_TILE];
  __shared__ int swl[M_TILE];

  const int tid  = threadIdx.x;
  const int lane = tid & 63;
  const int wv   = tid >> 6;            // 0..7
  const int quad = lane >> 4;
  const int colc = lane & 15;
  const int pb   = blockIdx.x;
  const int dir  = pb & 1;
  const int qb   = pb >> 1;
  const int tile = (qb & 1) ? (255 - (qb >> 1)) : (qb >> 1);

  if (tid < M_TILE) {
    int sw = sorted[tile * M_TILE + tid];
    swl[tid]  = sw;
    lenl[tid] = lengths[sw];
  }
  if (tid < 256) ((f32x4*)biasl)[tid] = ((const f32x4*)(biasg + dir * GATES))[tid];
  for (int i = tid; i < M_TILE * AROW / 2; i += 512) ((int*)A)[i] = 0;     // h=0 init
  for (int i = tid; i < 8 * 8 * 64; i += 512) c4[i] = (f32x4){0.f, 0.f, 0.f, 0.f};
  __syncthreads();

  if (tid < 256) { // char ids for the tile (via sorted ids)
    int w = tid >> 2, ch = tid & 3;
    ((i32x4*)charl)[tid] = ((const i32x4*)(char_ids + swl[w] * 16))[ch];
  }
  int Lmax = lenl[lane];
  for (int o = 32; o; o >>= 1) { int v = __shfl_xor(Lmax, o, 64); Lmax = Lmax > v ? Lmax : v; }
  __syncthreads();  // charl ready

  // x staging: wave w covers words 8w..8w+7, 8 lanes/word; split load/store (T14)
  const int xwl   = wv * 8 + (lane >> 3);
  const int xpart = lane & 7;
  auto x_load = [&](int tt) -> bf16x8 {
    int lw = lenl[xwl];
    int pos = (dir == 0) ? tt : (lw - 1 - tt);
    pos = pos < 0 ? 0 : (pos > 15 ? 15 : pos);
    int cid = charl[xwl * 16 + pos];
    return *(const bf16x8*)(embw + cid * EMBD + xpart * 8);
  };
  auto x_store = [&](bf16x8 e) {
    *(bf16x8*)(A + xwl * AROW + HID + xpart * 8) = e;
  };
  x_store(x_load(0));

  // step-invariant lane constants
  int lenw[4];
#pragma unroll
  for (int ct = 0; ct < 4; ++ct) lenw[ct] = lenl[ct * 16 + colc];
  const int h0    = colc * AROW + 32 * wv + quad;      // + ct*5248 + 4*rt (imm-foldable)
  const int obase = dir * 256 + 32 * wv + quad;        // + swl*512 + 4*rt
  const short* wp = wsw + ((size_t)dir * 64 + wv * 8) * 10 * 64 * 8 + lane * 8;
  f32x4* cptr = c4 + wv * (8 * 64) + lane;             // + rt*64

  __syncthreads();  // x(0) / zeros visible

  bf16x8 wc[10];      // single-buffered weight fragments (current tile)
  bf16x8 hx[4][10];   // B fragments, register-resident across the whole step

  auto ldw = [&](int rt) {
#pragma unroll
    for (int kk = 0; kk < 10; ++kk) wc[kk] = *(const bf16x8*)(wp + (rt * 10 + kk) * 512);
  };
  auto mfma_tile = [&](int rt, f32x4 (&acc)[4]) {
    f32x4 b4 = *(const f32x4*)(biasl + 128 * wv + 16 * rt + 4 * quad);
#pragma unroll
    for (int ct = 0; ct < 4; ++ct) acc[ct] = b4;
    __builtin_amdgcn_s_setprio(1);
#pragma unroll
    for (int kk = 0; kk < 10; ++kk)
#pragma unroll
      for (int ct = 0; ct < 4; ++ct)  // 4 independent acc chains -> MFMA ILP
        acc[ct] = __builtin_amdgcn_mfma_f32_16x16x32_bf16(wc[kk], hx[ct][kk], acc[ct], 0, 0, 0);
    __builtin_amdgcn_s_setprio(0);
  };
  auto epi_tile = [&](int t, int rt, f32x4 (&acc)[4]) {
    f32x4 co4 = cptr[rt * 64];                 // conflict-free ds_read_b128
    f32x4 cnew;
#pragma unroll
    for (int ct = 0; ct < 4; ++ct) {
      float ig = fsig(acc[ct][0]);
      float fg = fsig(acc[ct][1]);
      float gg = ftanhf(acc[ct][2]);
      float og = fsig(acc[ct][3]);
      float co_v = co4[ct];
      float c2 = fg * co_v + ig * gg;
      float h2 = og * ftanhf(c2);
      bool act = t < lenw[ct];
      cnew[ct] = act ? c2 : co_v;                               // freeze c when masked
      if (act) A[h0 + ct * 5248 + 4 * rt] = tobf(h2);           // freeze h when masked
      if (t == lenw[ct] - 1) {                                  // final h in fp32 (rare)
        int sw = swl[ct * 16 + colc];
        out[(size_t)sw * 512 + obase + 4 * rt] = h2;
      }
    }
    cptr[rt * 64] = cnew;   // one conflict-free ds_write_b128
  };

#pragma unroll 1
  for (int t = 0; t < Lmax; ++t) {
    // ---- pre-barrier loads: everything here reads only stable state ----
#pragma unroll
    for (int ct = 0; ct < 4; ++ct)
#pragma unroll
      for (int kk = 0; kk < 10; ++kk)
        hx[ct][kk] = *(const bf16x8*)(A + (ct * 16 + colc) * AROW + kk * 32 + quad * 8);
    bf16x8 e = x_load(t + 1);   // embw global load, latency spans the barrier
    ldw(0);                     // rt0 weights, latency spans the barrier
    __syncthreads();            // all waves snapshotted A; drains hx/wc0/e

    f32x4 accP[4], accQ[4];
    // pipelined tiles: mfma(rt) ; ldw(rt+1) ; epi(rt-1) -- epi consumes acc one
    // tile late (no scoreboard stall) and covers the wc load latency.
    mfma_tile(0, accP); ldw(1);
    mfma_tile(1, accQ); ldw(2); epi_tile(t, 0, accP);
    mfma_tile(2, accP); ldw(3); epi_tile(t, 1, accQ);
    mfma_tile(3, accQ); ldw(4); epi_tile(t, 2, accP);
    mfma_tile(4, accP); ldw(5); epi_tile(t, 3, accQ);
    mfma_tile(5, accQ); ldw(6); epi_tile(t, 4, accP);
    mfma_tile(6, accP); ldw(7); epi_tile(t, 5, accQ);
    mfma_tile(7, accQ);         epi_tile(t, 6, accP);
    x_store(e);                 // x(t+1) into A (vmem long since landed)
    epi_tile(t, 7, accQ);
    __syncthreads();            // h/x/c writes visible before next step's reads
  }
}

// ---------------- launch ----------------
extern "C" void kernel_launch(void* const* d_in, const int* in_sizes, int n_in,
                              void* d_out, int out_size, void* d_ws, size_t ws_size,
                              hipStream_t stream) {
  const int*   char_ids = (const int*)d_in[0];
  const int*   lengths  = (const int*)d_in[1];
  const float* emb      = (const float*)d_in[2];
  const float* Wihf     = (const float*)d_in[3];
  const float* Whhf     = (const float*)d_in[4];
  const float* bihf     = (const float*)d_in[5];
  const float* bhhf     = (const float*)d_in[6];
  const float* Wihb     = (const float*)d_in[7];
  const float* Whhb     = (const float*)d_in[8];
  const float* bihb     = (const float*)d_in[9];
  const float* bhhb     = (const float*)d_in[10];

  char* ws = (char*)d_ws;
  short* wsw   = (short*)(ws + OFF_WSW);
  short* embw  = (short*)(ws + OFF_EMB);
  float* biasg = (float*)(ws + OFF_BIAS);
  int*   sortd = (int*)(ws + OFF_SORT);
  int*   hist  = (int*)(ws + OFF_HIST);
  int*   basep = (int*)(ws + OFF_BASE);
  int*   cnt   = (int*)(ws + OFF_CNT);

  hipMemsetAsync(hist, 0, 192, stream);  // hist + base + cnt
  k_hist<<<64, 256, 0, stream>>>(lengths, hist);
  k_scan<<<1, 64, 0, stream>>>(hist, basep);
  k_scat<<<64, 256, 0, stream>>>(lengths, basep, cnt, sortd);
  prep_w<<<320, 256, 0, stream>>>(Wihf, Whhf, Wihb, Whhb, wsw);
  prep_misc<<<40, 256, 0, stream>>>(emb, bihf, bhhf, bihb, bhhb, embw, biasg);
  lstm_main<<<512, 512, 0, stream>>>(char_ids, lengths, wsw, embw, biasg, sortd,
                                     (float*)d_out);
}

// Round 5
// 554.321 us; speedup vs baseline: 2.0498x; 2.0498x over previous
//
#include <hip/hip_runtime.h>

// ---------------- problem constants ----------------
#define N_WORDS 16384
#define MAXL    16
#define VOCABSZ 128
#define EMBD    64
#define HID     256
#define GATES   1024        // 4*HID
#define KTOT    320         // HID + EMBD (x folded into K)
#define AROW    328         // A row stride in shorts (656 B = 640 + 16 pad)
#define M_TILE  64          // words per workgroup
#define NT      256         // word tiles (N_WORDS / M_TILE)

typedef __attribute__((ext_vector_type(8))) short bf16x8;  // 8 bf16 = 4 VGPRs
typedef __attribute__((ext_vector_type(4))) float f32x4;
typedef __attribute__((ext_vector_type(4))) int   i32x4;

// ---------------- workspace layout (bytes) ----------------
// wsw : swizzled weights, A-fragment order: [dir][R 0..63][kk 0..9][lane 0..63][8 bf16]
#define OFF_WSW   0ul          // 2*64*10*64*16 = 1310720
#define OFF_EMB   1310720ul    // 128*64 bf16 = 16384
#define OFF_BIAS  1327104ul    // 2*1024 f32 = 8192 (interleaved unit-major: [4*unit+type])
#define OFF_SORT  1335296ul    // 16384 ints = 65536
// cell state lives in LDS (64 KB/block) -- no global c buffer

__device__ inline short tobf(float f) {           // fp32 -> bf16 RNE
  unsigned u = __float_as_uint(f);
  unsigned r = (u + 0x7fffu + ((u >> 16) & 1u)) >> 16;
  return (short)r;
}
// raw transcendental units via inline asm
__device__ inline float aexp2(float x) { float r; asm("v_exp_f32 %0, %1" : "=v"(r) : "v"(x)); return r; }
__device__ inline float arcp(float x)  { float r; asm("v_rcp_f32 %0, %1" : "=v"(r) : "v"(x)); return r; }
__device__ inline float fsig(float x)   { return arcp(1.0f + aexp2(x * -1.4426950408889634f)); }
__device__ inline float ftanhf(float x) { return 1.0f - 2.0f * arcp(1.0f + aexp2(x * 2.8853900817779268f)); }

// ---------------- fused prep: weight swizzle + emb/bias prep (1 launch) ----------
// blocks 0..319: weight swizzle into MFMA *A*-fragment layout
//   A[m][k] for 16x16x32: m = lane&15, k = kk*32 + (lane>>4)*8 + j
//   row m of row-tile R: unit = 4R + (m>>2), gate type = m&3, gate row g = type*256+unit
// blocks 320..359: emb -> bf16, biases -> interleaved sum
__global__ void prep_all(const float* __restrict__ Wihf, const float* __restrict__ Whhf,
                         const float* __restrict__ Wihb, const float* __restrict__ Whhb,
                         const float* __restrict__ emb,
                         const float* __restrict__ bihf, const float* __restrict__ bhhf,
                         const float* __restrict__ bihb, const float* __restrict__ bhhb,
                         short* __restrict__ wsw, short* __restrict__ embw,
                         float* __restrict__ biasg) {
  int blk = blockIdx.x;
  if (blk < 320) {
    int id = blk * 256 + threadIdx.x;            // 2*64*10*64 = 81920
    int d    = id / 40960;
    int r    = id % 40960;
    int R    = r / 640;
    int r2   = r % 640;
    int kk   = r2 / 64;
    int lane = r2 % 64;
    int m    = lane & 15;
    int unit = R * 4 + (m >> 2);
    int ty   = m & 3;
    int g    = ty * 256 + unit;
    int kb   = kk * 32 + (lane >> 4) * 8;
    const float* Wih = d ? Wihb : Wihf;
    const float* Whh = d ? Whhb : Whhf;
    bf16x8 v;
#pragma unroll
    for (int j = 0; j < 8; ++j) {
      int k = kb + j;
      float f = (k < HID) ? Whh[g * HID + k] : Wih[g * EMBD + (k - HID)];
      v[j] = tobf(f);
    }
    ((bf16x8*)wsw)[id] = v;
  } else {
    int id = (blk - 320) * 256 + threadIdx.x;    // 8192 + 2048 = 10240
    if (id < VOCABSZ * EMBD) {
      embw[id] = tobf(emb[id]);
    } else {
      int r = id - VOCABSZ * EMBD;
      if (r < 2048) {
        int d = r >> 10, n = r & 1023;
        int g = (n & 3) * 256 + (n >> 2);
        biasg[r] = d ? (bihb[g] + bhhb[g]) : (bihf[g] + bhhf[g]);
      }
    }
  }
}

// ---------------- fused length-bucket sort (1 block, replaces hist+scan+scat) ----
// Order within a bin is arbitrary (equal-length words interchangeable) -- OK.
__global__ void k_sort(const int* __restrict__ lengths, int* __restrict__ sorted) {
  __shared__ int hist[16], base[16], cnt[16];
  int tid = threadIdx.x;                         // 1024 threads
  if (tid < 16) { hist[tid] = 0; cnt[tid] = 0; }
  __syncthreads();
  for (int i = tid; i < N_WORDS; i += 1024)
    atomicAdd(&hist[lengths[i] - 1], 1);
  __syncthreads();
  if (tid == 0) {
    int s = 0;
    for (int b = 0; b < 16; ++b) { base[b] = s; s += hist[b]; }
  }
  __syncthreads();
  for (int i = tid; i < N_WORDS; i += 1024) {
    int b = lengths[i] - 1;
    int p = base[b] + atomicAdd(&cnt[b], 1);
    sorted[p] = i;
  }
}

// ---------------- main fused BiLSTM kernel ----------------
// Round-2 structure (proven no-spill) + T5 setprio + wave-staggered tile order
// (rt = i ^ (wv&4): half the waves start at tile 4 -> vmem/MFMA phases interleave
// across waves instead of colliding) + T14 x-gather split (load early/store late).
// Weights = MFMA A-operand, [h|x] = B-operand; lane owns unit 32wv+4rt+quad,
// word ct*16+colc; acc regs = i,f,g,o. Cell state: LDS f32x4 per (wv,rt,lane).
__global__ __launch_bounds__(512, 1) void lstm_main(
    const int* __restrict__ char_ids, const int* __restrict__ lengths,
    const short* __restrict__ wsw, const short* __restrict__ embw,
    const float* __restrict__ biasg, const int* __restrict__ sorted,
    float* __restrict__ out) {
  __shared__ __align__(16) short A[M_TILE * AROW];   // [word][ h(256) | x(64) | pad(8) ] bf16
  __shared__ __align__(16) int   charl[M_TILE * 16];
  __shared__ __align__(16) float biasl[GATES];
  __shared__ __align__(16) f32x4 c4[8 * 8 * 64];     // [wv][rt][lane] cell state, 64 KB
  __shared__ int lenl[M_TILE];
  __shared__ int swl[M_TILE];

  const int tid  = threadIdx.x;
  const int lane = tid & 63;
  const int wv   = tid >> 6;            // 0..7
  const int quad = lane >> 4;
  const int colc = lane & 15;
  const int xo   = wv & 4;              // wave-stagger: tile order i ^ xo
  const int pb   = blockIdx.x;
  const int dir  = pb & 1;
  const int qb   = pb >> 1;
  const int tile = (qb & 1) ? (255 - (qb >> 1)) : (qb >> 1);

  if (tid < M_TILE) {
    int sw = sorted[tile * M_TILE + tid];
    swl[tid]  = sw;
    lenl[tid] = lengths[sw];
  }
  if (tid < 256) ((f32x4*)biasl)[tid] = ((const f32x4*)(biasg + dir * GATES))[tid];
  for (int i = tid; i < M_TILE * AROW / 2; i += 512) ((int*)A)[i] = 0;     // h=0 init
  for (int i = tid; i < 8 * 8 * 64; i += 512) c4[i] = (f32x4){0.f, 0.f, 0.f, 0.f};
  __syncthreads();

  if (tid < 256) { // char ids for the tile (via sorted ids)
    int w = tid >> 2, ch = tid & 3;
    ((i32x4*)charl)[tid] = ((const i32x4*)(char_ids + swl[w] * 16))[ch];
  }
  int Lmax = lenl[lane];
  for (int o = 32; o; o >>= 1) { int v = __shfl_xor(Lmax, o, 64); Lmax = Lmax > v ? Lmax : v; }
  __syncthreads();  // charl ready

  // x staging: wave w covers words 8w..8w+7, 8 lanes/word; split load/store (T14)
  const int xwl   = wv * 8 + (lane >> 3);
  const int xpart = lane & 7;
  auto x_load = [&](int tt) -> bf16x8 {
    int lw = lenl[xwl];
    int pos = (dir == 0) ? tt : (lw - 1 - tt);
    pos = pos < 0 ? 0 : (pos > 15 ? 15 : pos);
    int cid = charl[xwl * 16 + pos];
    return *(const bf16x8*)(embw + cid * EMBD + xpart * 8);
  };
  auto x_store = [&](bf16x8 e) {
    *(bf16x8*)(A + xwl * AROW + HID + xpart * 8) = e;
  };
  x_store(x_load(0));

  // step-invariant lane constants
  int lenw[4];
#pragma unroll
  for (int ct = 0; ct < 4; ++ct) lenw[ct] = lenl[ct * 16 + colc];
  const int h0    = colc * AROW + 32 * wv + quad;      // + ct*5248 + 4*rt
  const int obase = dir * 256 + 32 * wv + quad;        // + swl*512 + 4*rt
  const short* wp = wsw + ((size_t)dir * 64 + wv * 8) * 10 * 64 * 8 + lane * 8;
  f32x4* cptr = c4 + wv * (8 * 64) + lane;             // + rt*64

  __syncthreads();  // x(0) / zeros visible

  // preload this wave's first tile (rt = xo); ping-pong keeps weights hot across steps
  bf16x8 wA[10], wB[10];
#pragma unroll
  for (int kk = 0; kk < 10; ++kk) wA[kk] = *(const bf16x8*)(wp + (xo * 10 + kk) * 512);

#pragma unroll 1
  for (int t = 0; t < Lmax; ++t) {
    bf16x8 hx[4][10];  // B fragments: lane = B[k = kk*32 + quad*8 + j][n = ct*16 + colc]
#pragma unroll
    for (int ct = 0; ct < 4; ++ct)
#pragma unroll
      for (int kk = 0; kk < 10; ++kk)
        hx[ct][kk] = *(const bf16x8*)(A + (ct * 16 + colc) * AROW + kk * 32 + quad * 8);
    bf16x8 e = x_load(t + 1);   // embw global load: latency spans the whole step

    __syncthreads();  // all waves snapshotted A -> safe to overwrite h/x below

    auto wtile = [&](int rt, bf16x8(&wc)[10], bf16x8(&wn)[10], int pre) {
      // prefetch next tile in THIS wave's order (last tile warms next step's first)
#pragma unroll
      for (int kk = 0; kk < 10; ++kk) wn[kk] = *(const bf16x8*)(wp + (pre * 10 + kk) * 512);
      f32x4 co4 = cptr[rt * 64];                 // LDS c, covered by the MFMA block
      f32x4 bias4 = *(const f32x4*)(biasl + 128 * wv + 16 * rt + 4 * quad);
      f32x4 acc[4];
#pragma unroll
      for (int ct = 0; ct < 4; ++ct) acc[ct] = bias4;
      __builtin_amdgcn_s_setprio(1);
#pragma unroll
      for (int kk = 0; kk < 10; ++kk)
#pragma unroll
        for (int ct = 0; ct < 4; ++ct)  // 4 independent acc chains -> MFMA ILP
          acc[ct] = __builtin_amdgcn_mfma_f32_16x16x32_bf16(wc[kk], hx[ct][kk], acc[ct], 0, 0, 0);
      __builtin_amdgcn_s_setprio(0);

      f32x4 cnew;
#pragma unroll
      for (int ct = 0; ct < 4; ++ct) {
        // lane-private epilogue: regs = i,f,g,o of (unit 32wv+4rt+quad, word ct*16+colc)
        float ig = fsig(acc[ct][0]);
        float fg = fsig(acc[ct][1]);
        float gg = ftanhf(acc[ct][2]);
        float og = fsig(acc[ct][3]);
        float co_v = co4[ct];
        float c2 = fg * co_v + ig * gg;
        float h2 = og * ftanhf(c2);
        bool act = t < lenw[ct];
        cnew[ct] = act ? c2 : co_v;                               // freeze c when masked
        if (act) A[h0 + ct * 5248 + 4 * rt] = tobf(h2);           // freeze h when masked
        if (t == lenw[ct] - 1) {                                  // final h in fp32 (rare)
          int sw = swl[ct * 16 + colc];
          out[(size_t)sw * 512 + obase + 4 * rt] = h2;
        }
      }
      cptr[rt * 64] = cnew;   // one conflict-free ds_write_b128
    };

#pragma unroll 1
    for (int i = 0; i < 8; i += 2) {   // ping-pong weight buffers; wave-rotated order
      wtile(i ^ xo,       wA, wB, ((i + 1) & 7) ^ xo);
      wtile((i + 1) ^ xo, wB, wA, ((i + 2) & 7) ^ xo);
    }

    x_store(e);        // x(t+1) into A (global load long since landed)
    __syncthreads();   // h/x/c writes visible before next step's reads
  }
}

// ---------------- launch ----------------
extern "C" void kernel_launch(void* const* d_in, const int* in_sizes, int n_in,
                              void* d_out, int out_size, void* d_ws, size_t ws_size,
                              hipStream_t stream) {
  const int*   char_ids = (const int*)d_in[0];
  const int*   lengths  = (const int*)d_in[1];
  const float* emb      = (const float*)d_in[2];
  const float* Wihf     = (const float*)d_in[3];
  const float* Whhf     = (const float*)d_in[4];
  const float* bihf     = (const float*)d_in[5];
  const float* bhhf     = (const float*)d_in[6];
  const float* Wihb     = (const float*)d_in[7];
  const float* Whhb     = (const float*)d_in[8];
  const float* bihb     = (const float*)d_in[9];
  const float* bhhb     = (const float*)d_in[10];

  char* ws = (char*)d_ws;
  short* wsw   = (short*)(ws + OFF_WSW);
  short* embw  = (short*)(ws + OFF_EMB);
  float* biasg = (float*)(ws + OFF_BIAS);
  int*   sortd = (int*)(ws + OFF_SORT);

  k_sort<<<1, 1024, 0, stream>>>(lengths, sortd);
  prep_all<<<360, 256, 0, stream>>>(Wihf, Whhf, Wihb, Whhb, emb,
                                    bihf, bhhf, bihb, bhhb, wsw, embw, biasg);
  lstm_main<<<512, 512, 0, stream>>>(char_ids, lengths, wsw, embw, biasg, sortd,
                                     (float*)d_out);
}

// Round 6
// 405.154 us; speedup vs baseline: 2.8045x; 1.3682x over previous
//
#include <hip/hip_runtime.h>

// ---------------- problem constants ----------------
#define N_WORDS 16384
#define MAXL    16
#define VOCABSZ 128
#define EMBD    64
#define HID     256
#define GATES   1024        // 4*HID
#define KTOT    320         // HID + EMBD (x folded into K)
#define AROW    328         // A row stride in shorts (656 B = 640 + 16 pad)
#define M_TILE  64          // words per workgroup
#define NT      256         // word tiles (N_WORDS / M_TILE)

typedef __attribute__((ext_vector_type(8))) short bf16x8;  // 8 bf16 = 4 VGPRs
typedef __attribute__((ext_vector_type(4))) float f32x4;
typedef __attribute__((ext_vector_type(4))) int   i32x4;

// ---------------- workspace layout (bytes) ----------------
// wsw : swizzled weights, A-fragment order: [dir][R 0..63][kk 0..9][lane 0..63][8 bf16]
#define OFF_WSW   0ul          // 2*64*10*64*16 = 1310720
#define OFF_EMB   1310720ul    // 128*64 bf16 = 16384
#define OFF_BIAS  1327104ul    // 2*1024 f32 = 8192 (interleaved unit-major: [4*unit+type])
#define OFF_SORT  1335296ul    // 16384 ints = 65536
// cell state lives in LDS (64 KB/block) -- no global c buffer

__device__ inline short tobf(float f) {           // fp32 -> bf16 RNE
  unsigned u = __float_as_uint(f);
  unsigned r = (u + 0x7fffu + ((u >> 16) & 1u)) >> 16;
  return (short)r;
}
// raw transcendental units via inline asm
__device__ inline float aexp2(float x) { float r; asm("v_exp_f32 %0, %1" : "=v"(r) : "v"(x)); return r; }
__device__ inline float arcp(float x)  { float r; asm("v_rcp_f32 %0, %1" : "=v"(r) : "v"(x)); return r; }
__device__ inline float fsig(float x)   { return arcp(1.0f + aexp2(x * -1.4426950408889634f)); }
__device__ inline float ftanhf(float x) { return 1.0f - 2.0f * arcp(1.0f + aexp2(x * 2.8853900817779268f)); }

// ---------------- fused prep: weight swizzle + emb/bias + length-sort (1 launch) --
// blocks 0..319 : weight swizzle into MFMA *A*-fragment layout
//   A[m][k] for 16x16x32: m = lane&15, k = kk*32 + (lane>>4)*8 + j
//   row m of row-tile R: unit = 4R + (m>>2), gate type = m&3, gate row g = type*256+unit
// blocks 320..359: emb -> bf16, biases -> interleaved sum
// block 360      : single-block length-bucket sort (bin order arbitrary -- OK)
__global__ void prep_all(const float* __restrict__ Wihf, const float* __restrict__ Whhf,
                         const float* __restrict__ Wihb, const float* __restrict__ Whhb,
                         const float* __restrict__ emb,
                         const float* __restrict__ bihf, const float* __restrict__ bhhf,
                         const float* __restrict__ bihb, const float* __restrict__ bhhb,
                         const int* __restrict__ lengths,
                         short* __restrict__ wsw, short* __restrict__ embw,
                         float* __restrict__ biasg, int* __restrict__ sorted) {
  __shared__ int hist[16], base[16], cnt[16];
  int blk = blockIdx.x;
  if (blk < 320) {
    int id = blk * 256 + threadIdx.x;            // 2*64*10*64 = 81920
    int d    = id / 40960;
    int r    = id % 40960;
    int R    = r / 640;
    int r2   = r % 640;
    int kk   = r2 / 64;
    int lane = r2 % 64;
    int m    = lane & 15;
    int unit = R * 4 + (m >> 2);
    int ty   = m & 3;
    int g    = ty * 256 + unit;
    int kb   = kk * 32 + (lane >> 4) * 8;
    const float* Wih = d ? Wihb : Wihf;
    const float* Whh = d ? Whhb : Whhf;
    bf16x8 v;
#pragma unroll
    for (int j = 0; j < 8; ++j) {
      int k = kb + j;
      float f = (k < HID) ? Whh[g * HID + k] : Wih[g * EMBD + (k - HID)];
      v[j] = tobf(f);
    }
    ((bf16x8*)wsw)[id] = v;
  } else if (blk < 360) {
    int id = (blk - 320) * 256 + threadIdx.x;    // 8192 + 2048 = 10240
    if (id < VOCABSZ * EMBD) {
      embw[id] = tobf(emb[id]);
    } else {
      int r = id - VOCABSZ * EMBD;
      if (r < 2048) {
        int d = r >> 10, n = r & 1023;
        int g = (n & 3) * 256 + (n >> 2);
        biasg[r] = d ? (bihb[g] + bhhb[g]) : (bihf[g] + bhhf[g]);
      }
    }
  } else {  // blk == 360: length-bucket sort, 256 threads
    int tid = threadIdx.x;
    if (tid < 16) { hist[tid] = 0; cnt[tid] = 0; }
    __syncthreads();
    for (int i = tid; i < N_WORDS; i += 256)
      atomicAdd(&hist[lengths[i] - 1], 1);
    __syncthreads();
    if (tid == 0) {
      int s = 0;
      for (int b = 0; b < 16; ++b) { base[b] = s; s += hist[b]; }
    }
    __syncthreads();
    for (int i = tid; i < N_WORDS; i += 256) {
      int b = lengths[i] - 1;
      int p = base[b] + atomicAdd(&cnt[b], 1);
      sorted[p] = i;
    }
  }
}

// ---------------- main fused BiLSTM kernel (VERBATIM round-2 body) ----------------
// Weights are the MFMA A-operand (rows = 4 units x 4 gates, unit-major interleave),
// [h|x] is the B-operand. C tile: row=quad*4+reg, col=lane&15
// => lane's 4 acc regs = i,f,g,o of ONE (unit,word). No cross-lane transpose.
// 8 waves x 8 row-tiles: lane owns unit u = 32*wv + 4*rt + quad, word w = ct*16 + colc.
// Cell state: LDS, f32x4 per (wv,rt,lane) -> 1 conflict-free ds_read_b128/wtile,
// on lgkmcnt (decoupled from the vmcnt weight-prefetch chain).
// NOTE (R4/R5 lessons): this live set is at the 256-reg/wave edge. Do NOT hold
// extra values across the rt loop (x split spilled: +173 MB scratch writes, -46%).
__global__ __launch_bounds__(512, 1) void lstm_main(
    const int* __restrict__ char_ids, const int* __restrict__ lengths,
    const short* __restrict__ wsw, const short* __restrict__ embw,
    const float* __restrict__ biasg, const int* __restrict__ sorted,
    float* __restrict__ out) {
  __shared__ __align__(16) short A[M_TILE * AROW];   // [word][ h(256) | x(64) | pad(8) ] bf16
  __shared__ __align__(16) int   charl[M_TILE * 16];
  __shared__ __align__(16) float biasl[GATES];
  __shared__ __align__(16) f32x4 c4[8 * 8 * 64];     // [wv][rt][lane] cell state, 64 KB
  __shared__ int lenl[M_TILE];
  __shared__ int swl[M_TILE];

  const int tid  = threadIdx.x;
  const int lane = tid & 63;
  const int wv   = tid >> 6;            // 0..7
  const int quad = lane >> 4;
  const int colc = lane & 15;
  const int pb   = blockIdx.x;
  const int dir  = pb & 1;
  const int qb   = pb >> 1;
  const int tile = (qb & 1) ? (255 - (qb >> 1)) : (qb >> 1);

  if (tid < M_TILE) {
    int sw = sorted[tile * M_TILE + tid];
    swl[tid]  = sw;
    lenl[tid] = lengths[sw];
  }
  if (tid < 256) ((f32x4*)biasl)[tid] = ((const f32x4*)(biasg + dir * GATES))[tid];
  for (int i = tid; i < M_TILE * AROW / 2; i += 512) ((int*)A)[i] = 0;     // h=0 init
  for (int i = tid; i < 8 * 8 * 64; i += 512) c4[i] = (f32x4){0.f, 0.f, 0.f, 0.f};
  __syncthreads();

  if (tid < 256) { // char ids for the tile (via sorted ids)
    int w = tid >> 2, ch = tid & 3;
    ((i32x4*)charl)[tid] = ((const i32x4*)(char_ids + swl[w] * 16))[ch];
  }
  int Lmax = lenl[lane];
  for (int o = 32; o; o >>= 1) { int v = __shfl_xor(Lmax, o, 64); Lmax = Lmax > v ? Lmax : v; }
  __syncthreads();  // charl ready

  // stage x for timestep tt into A cols [256,320): wave w covers words 8w..8w+7, 8 lanes/word
  auto gather_x = [&](int tt) {
    int wl = wv * 8 + (lane >> 3);
    int part = lane & 7;
    int lw = lenl[wl];
    int pos = (dir == 0) ? tt : (lw - 1 - tt);
    pos = pos < 0 ? 0 : (pos > 15 ? 15 : pos);
    int cid = charl[wl * 16 + pos];
    bf16x8 e = *(const bf16x8*)(embw + cid * EMBD + part * 8);
    *(bf16x8*)(A + wl * AROW + HID + part * 8) = e;
  };
  gather_x(0);

  // step-invariant lane constants (word dimension, per col-tile ct)
  int lenw[4], hadrb[4], oadr[4];
#pragma unroll
  for (int ct = 0; ct < 4; ++ct) {
    int wl = ct * 16 + colc;
    lenw[ct]  = lenl[wl];
    hadrb[ct] = wl * AROW + 32 * wv + quad;                  // + 4*rt : bf16 h slot in A
    oadr[ct]  = swl[wl] * 512 + dir * 256 + 32 * wv + quad;  // + 4*rt : fp32 out slot
  }
  const short* wp = wsw + ((size_t)dir * 64 + wv * 8) * 10 * 64 * 8 + lane * 8;
  f32x4* cptr = c4 + wv * (8 * 64) + lane;   // + rt*64

  __syncthreads();  // x / zeros visible

  // preload rt=0 weight fragments once; ping-pong keeps them hot across steps
  bf16x8 wA[10], wB[10];
#pragma unroll
  for (int kk = 0; kk < 10; ++kk) wA[kk] = *(const bf16x8*)(wp + kk * 512);

#pragma unroll 1
  for (int t = 0; t < Lmax; ++t) {
    bf16x8 hx[4][10];  // B fragments: lane = B[k = kk*32 + quad*8 + j][n = ct*16 + colc]
#pragma unroll
    for (int ct = 0; ct < 4; ++ct)
#pragma unroll
      for (int kk = 0; kk < 10; ++kk)
        hx[ct][kk] = *(const bf16x8*)(A + (ct * 16 + colc) * AROW + kk * 32 + quad * 8);

    __syncthreads();  // all waves snapshotted A -> safe to overwrite h/x below

    auto wtile = [&](int rt, bf16x8(&wc)[10], bf16x8(&wn)[10], int pre) {
      // prefetch next row-tile's weight frags (pre=0 at rt=7 warms next step's rt0)
#pragma unroll
      for (int kk = 0; kk < 10; ++kk) wn[kk] = *(const bf16x8*)(wp + (pre * 10 + kk) * 512);
      f32x4 co4 = cptr[rt * 64];                 // LDS c, covered by the MFMA block
      // bias for lane's unit: one f32x4 = (b_i, b_f, b_g, b_o)
      f32x4 bias4 = *(const f32x4*)(biasl + 128 * wv + 16 * rt + 4 * quad);
      f32x4 acc[4];
#pragma unroll
      for (int ct = 0; ct < 4; ++ct) acc[ct] = bias4;
#pragma unroll
      for (int kk = 0; kk < 10; ++kk)
#pragma unroll
        for (int ct = 0; ct < 4; ++ct)  // 4 independent acc chains -> MFMA ILP
          acc[ct] = __builtin_amdgcn_mfma_f32_16x16x32_bf16(wc[kk], hx[ct][kk], acc[ct], 0, 0, 0);

      f32x4 cnew;
#pragma unroll
      for (int ct = 0; ct < 4; ++ct) {
        // lane-private epilogue: regs = i,f,g,o of (unit 32wv+4rt+quad, word ct*16+colc)
        float ig = fsig(acc[ct][0]);
        float fg = fsig(acc[ct][1]);
        float gg = ftanhf(acc[ct][2]);
        float og = fsig(acc[ct][3]);
        float co_v = co4[ct];
        float c2 = fg * co_v + ig * gg;
        float h2 = og * ftanhf(c2);
        bool act = t < lenw[ct];
        cnew[ct] = act ? c2 : co_v;                          // freeze c when masked
        if (act) A[hadrb[ct] + 4 * rt] = tobf(h2);           // freeze h when masked
        if (t == lenw[ct] - 1) out[oadr[ct] + 4 * rt] = h2;  // final h in fp32
      }
      cptr[rt * 64] = cnew;   // one conflict-free ds_write_b128
    };

#pragma unroll 1
    for (int rt2 = 0; rt2 < 8; rt2 += 2) {   // ping-pong weight buffers, static indices
      wtile(rt2,     wA, wB, rt2 + 1);
      wtile(rt2 + 1, wB, wA, (rt2 + 2) & 7); // rt=7 prefetches next step's rt0
    }

    gather_x(t + 1);   // x for next step (clamped; dead steps are masked)
    __syncthreads();   // h/x writes visible before next step's reads
  }
}

// ---------------- launch ----------------
extern "C" void kernel_launch(void* const* d_in, const int* in_sizes, int n_in,
                              void* d_out, int out_size, void* d_ws, size_t ws_size,
                              hipStream_t stream) {
  const int*   char_ids = (const int*)d_in[0];
  const int*   lengths  = (const int*)d_in[1];
  const float* emb      = (const float*)d_in[2];
  const float* Wihf     = (const float*)d_in[3];
  const float* Whhf     = (const float*)d_in[4];
  const float* bihf     = (const float*)d_in[5];
  const float* bhhf     = (const float*)d_in[6];
  const float* Wihb     = (const float*)d_in[7];
  const float* Whhb     = (const float*)d_in[8];
  const float* bihb     = (const float*)d_in[9];
  const float* bhhb     = (const float*)d_in[10];

  char* ws = (char*)d_ws;
  short* wsw   = (short*)(ws + OFF_WSW);
  short* embw  = (short*)(ws + OFF_EMB);
  float* biasg = (float*)(ws + OFF_BIAS);
  int*   sortd = (int*)(ws + OFF_SORT);

  prep_all<<<361, 256, 0, stream>>>(Wihf, Whhf, Wihb, Whhb, emb,
                                    bihf, bhhf, bihb, bhhb, lengths,
                                    wsw, embw, biasg, sortd);
  lstm_main<<<512, 512, 0, stream>>>(char_ids, lengths, wsw, embw, biasg, sortd,
                                     (float*)d_out);
}